// Round 20
// baseline (573.462 us; speedup 1.0000x reference)
//
#include <hip/hip_runtime.h>
#include <hip/hip_bf16.h>
#include <stdint.h>

// GatheringLoss: score = q[32768x512] @ items[4096x512]^T, idx = argmax_row,
// out = mean((q - items[idx])^2).
// R20: addressing/layout cleanup on green R19 (math bit-identical).
//  - pk2[g][kc64][col][64B]: lane's 32B B frag = ONE contiguous i32x8 load;
//    per-iter addr delta = uniform (g*8+kc64)<<15 (SALU); lane offsets hoisted.
//  - A LDS pitch 528 (16B pad; 4-way b128 spread, no XOR): A frag = one
//    contiguous i32x8 at Aptr + kc64*64 with COMPILE-TIME offset (g-outer,
//    kc64 unrolled). Zero per-iter A address VALU. Linear prologue.
//  - fold / butterfly / sV-sI merge / MSE epilogue byte-identical to R19.
// Theory: R19's residual ~190k cyc/SIMD was VALU (33%) = address arith +
// brace-built i32x8 assembly (~330 VALU/iter). This removes most of it.
// ws: [0,2MB) pk2 fp8 packed items | [+4MB) ihl fp16 items | [+1KB) partials

#define D_DIM 512
#define M_ITEMS 4096
#define N_ROWS 32768
#define BM 128
#define GCOLS 512            // cols per group
#define NG (M_ITEMS / GCOLS) // 8 groups
#define APITCH 528           // A LDS row pitch (512 + 16B pad)

typedef _Float16 half8 __attribute__((ext_vector_type(8)));
typedef _Float16 half4h __attribute__((ext_vector_type(4)));
typedef float f32x16 __attribute__((ext_vector_type(16)));
typedef float f32x4v __attribute__((ext_vector_type(4)));
typedef int i32x8 __attribute__((ext_vector_type(8)));

__device__ inline unsigned pack4_fp8(float a, float b, float c, float d) {
  int v = 0;
  v = __builtin_amdgcn_cvt_pk_fp8_f32(a, b, v, false); // bytes 0,1
  v = __builtin_amdgcn_cvt_pk_fp8_f32(c, d, v, true);  // bytes 2,3
  return (unsigned)v;
}

__global__ __launch_bounds__(256) void cast_f32_f16(
    const float* __restrict__ in, _Float16* __restrict__ out, int n4) {
  const int stride = gridDim.x * blockDim.x;
  for (int i = blockIdx.x * blockDim.x + threadIdx.x; i < n4; i += stride) {
    const f32x4v v = reinterpret_cast<const f32x4v*>(in)[i];
    half4h h;
    h.x = (_Float16)v.x;
    h.y = (_Float16)v.y;
    h.z = (_Float16)v.z;
    h.w = (_Float16)v.w;
    reinterpret_cast<half4h*>(out)[i] = h;
  }
}

// pk2[g][kc64][c][64]: 16B unit u -> q=u&3, c=(u>>2)&511, kc64=(u>>11)&7,
// g=u>>14. Holds items[g*512+c][kc64*64 + q*16 .. +16) as fp8.
__global__ __launch_bounds__(256) void pack_items_fp8(
    const float* __restrict__ itf, unsigned char* __restrict__ pk2) {
  const int u = blockIdx.x * blockDim.x + threadIdx.x; // 0..131071
  const int q = u & 3;
  const int c = (u >> 2) & 511;
  const int kc64 = (u >> 11) & 7;
  const int g = u >> 14;
  const int m = g * 512 + c;
  const float* src = itf + (size_t)m * D_DIM + kc64 * 64 + q * 16;
  const f32x4v a = *reinterpret_cast<const f32x4v*>(src);
  const f32x4v b = *reinterpret_cast<const f32x4v*>(src + 4);
  const f32x4v cc = *reinterpret_cast<const f32x4v*>(src + 8);
  const f32x4v d = *reinterpret_cast<const f32x4v*>(src + 12);
  uint4 o;
  o.x = pack4_fp8(a.x, a.y, a.z, a.w);
  o.y = pack4_fp8(b.x, b.y, b.z, b.w);
  o.z = pack4_fp8(cc.x, cc.y, cc.z, cc.w);
  o.w = pack4_fp8(d.x, d.y, d.z, d.w);
  *reinterpret_cast<uint4*>(pk2 + (size_t)u * 16) = o;
}

__global__ __launch_bounds__(512, 2) void score_mse(
    const float* __restrict__ qf, const unsigned char* __restrict__ pk2,
    const _Float16* __restrict__ ihl, float* __restrict__ partials) {
  __shared__ __align__(16) unsigned char Alds8[BM * APITCH]; // 67.5 KiB
  __shared__ float sV[4][BM];
  __shared__ int sI[4][BM];
  __shared__ float sSum[8];

  const int t = threadIdx.x; // 0..511
  const int lane = t & 63;
  const int wid = t >> 6;  // 0..7
  const int wm = wid >> 2; // 0..1 (row half: 64 rows)
  const int wn = wid & 3;  // 0..3 (col quarter of 512: 128 cols)
  const int l31 = lane & 31;
  const int hsel = lane >> 5; // 0..1

  // T1: XCD chunking (grid 256 = 8 XCD x 32)
  const int bid = blockIdx.x;
  const int rb = (bid & 7) * 32 + (bid >> 3);
  const int row0 = rb * BM;

  // --- prologue: cast this block's 128 q rows f32->fp8 into Alds8 (linear
  // within row, pitch 528). 4096 16B-units, 8 per thread.
#pragma unroll
  for (int i = 0; i < 8; ++i) {
    const int f = i * 512 + t; // 0..4095
    const int r = f >> 5;
    const int u = f & 31;
    const float* src = qf + (size_t)(row0 + r) * D_DIM + u * 16;
    const f32x4v a = *(const f32x4v*)(src);
    const f32x4v b = *(const f32x4v*)(src + 4);
    const f32x4v c = *(const f32x4v*)(src + 8);
    const f32x4v d = *(const f32x4v*)(src + 12);
    uint4 o;
    o.x = pack4_fp8(a.x, a.y, a.z, a.w);
    o.y = pack4_fp8(b.x, b.y, b.z, b.w);
    o.z = pack4_fp8(c.x, c.y, c.z, c.w);
    o.w = pack4_fp8(d.x, d.y, d.z, d.w);
    *reinterpret_cast<uint4*>(Alds8 + (size_t)r * APITCH + u * 16) = o;
  }
  __syncthreads();

  f32x16 acc[2][4];
#pragma unroll
  for (int fr = 0; fr < 2; ++fr)
#pragma unroll
    for (int fc = 0; fc < 4; ++fc) acc[fr][fc] = (f32x16)(0.0f);
  float rmax[2][16];
  unsigned rid16[16]; // packed idx: bits [15:0]=fr0, [31:16]=fr1
#pragma unroll
  for (int rg = 0; rg < 16; ++rg) {
    rmax[0][rg] = -3.0e38f;
    rmax[1][rg] = -3.0e38f;
    rid16[rg] = 0u;
  }

  // Hoisted lane bases. A: row = wm*64 + {l31, 32+l31}, k-half by hsel.
  const unsigned char* Aptr0 =
      Alds8 + (size_t)(wm * 64 + l31) * APITCH + hsel * 32;
  const unsigned char* Aptr1 = Aptr0 + (size_t)32 * APITCH;
  // B: lane offset within a (g,kc64) 32KB panel: col*64 + hsel*32.
  const size_t bo0 = ((size_t)(wn * 128 + l31) << 6) + hsel * 32;

#pragma unroll 1
  for (int g = 0; g < NG; ++g) {
    const unsigned char* pgrp = pk2 + ((size_t)g << 18); // g * 256KB
#pragma unroll
    for (int kc64 = 0; kc64 < 8; ++kc64) {
      const unsigned char* pchunk = pgrp + (kc64 << 15); // + kc64 * 32KB
      const i32x8 av0 = *(const i32x8*)(Aptr0 + kc64 * 64);
      const i32x8 av1 = *(const i32x8*)(Aptr1 + kc64 * 64);
#pragma unroll
      for (int fc = 0; fc < 4; ++fc) {
        const i32x8 bv = *(const i32x8*)(pchunk + bo0 + fc * 2048);
        // cbsz=0 (fp8 e4m3), blgp=0, scale 127 = x1.0 (exact)
        acc[0][fc] = __builtin_amdgcn_mfma_scale_f32_32x32x64_f8f6f4(
            av0, bv, acc[0][fc], 0, 0, 0, 127, 0, 127);
        acc[1][fc] = __builtin_amdgcn_mfma_scale_f32_32x32x64_f8f6f4(
            av1, bv, acc[1][fc], 0, 0, 0, 127, 0, 127);
      }
    }
    // --- group fold (trusted R16/R19 code): cols ascend with fc and g ->
    // strict > keeps lowest index.
    {
      const int colbase_ = g * GCOLS + wn * 128 + l31;
#pragma unroll
      for (int fr = 0; fr < 2; ++fr)
#pragma unroll
        for (int rg = 0; rg < 16; ++rg) {
          float v_ = acc[fr][0][rg];
          int c_ = colbase_;
#pragma unroll
          for (int fc = 1; fc < 4; ++fc) {
            const float vv_ = acc[fr][fc][rg];
            if (vv_ > v_) {
              v_ = vv_;
              c_ = colbase_ + fc * 32;
            }
          }
          if (v_ > rmax[fr][rg]) {
            rmax[fr][rg] = v_;
            rid16[rg] = (rid16[rg] & (fr ? 0x0000FFFFu : 0xFFFF0000u)) |
                        ((unsigned)c_ << (fr * 16));
          }
        }
#pragma unroll
      for (int fr = 0; fr < 2; ++fr)
#pragma unroll
        for (int fc = 0; fc < 4; ++fc) acc[fr][fc] = (f32x16)(0.0f);
    }
  }

  // --- argmax block reduce. C/D layout (m74/m101): col = lane&31,
  // row = (rg&3) + 8*(rg>>2) + 4*(lane>>5).
  float bv = -3.0e38f;
  int bi = 0;
#pragma unroll
  for (int fr = 0; fr < 2; ++fr)
#pragma unroll
    for (int rg = 0; rg < 16; ++rg) {
      float v = rmax[fr][rg];
      int c = (int)((rid16[rg] >> (fr * 16)) & 0xFFFFu);
#pragma unroll
      for (int m = 1; m < 32; m <<= 1) {
        const float ov = __shfl_xor(v, m, 64);
        const int oc = __shfl_xor(c, m, 64);
        if (ov > v || (ov == v && oc < c)) {
          v = ov;
          c = oc;
        }
      }
      if (l31 == fr * 16 + rg) {
        bv = v;
        bi = c;
      }
    }
  const int e = l31;
  const int row_local =
      wm * 64 + (e >> 4) * 32 + ((e & 3) + 8 * ((e >> 2) & 3)) + 4 * hsel;

  sV[wn][row_local] = bv;
  sI[wn][row_local] = bi;
  __syncthreads();
  if (t < BM) {
    float fv = sV[0][t];
    int fi = sI[0][t];
#pragma unroll
    for (int w = 1; w < 4; ++w) {
      const float v = sV[w][t];
      const int ii = sI[w][t];
      if (v > fv || (v == fv && ii < fi)) {
        fv = v;
        fi = ii;
      }
    }
    sI[0][t] = fi; // merged winner per row
  }
  __syncthreads();

  // --- fused MSE epilogue: wave wid handles rows wid*16..+15.
  // q EXACT from global f32; gathered item from fp16 ihl.
  float lsum = 0.0f;
#pragma unroll 1
  for (int rr = 0; rr < 16; ++rr) {
    const int r = wid * 16 + rr;
    const int fi = sI[0][r];
    const float* qr = qf + (size_t)(row0 + r) * D_DIM + lane * 8;
    const f32x4v a0 = *(const f32x4v*)(qr);
    const f32x4v a1 = *(const f32x4v*)(qr + 4);
    const half8 ag = *(const half8*)(ihl + (size_t)fi * D_DIM + lane * 8);
    const float d0 = a0.x - (float)ag[0], d1 = a0.y - (float)ag[1];
    const float d2 = a0.z - (float)ag[2], d3 = a0.w - (float)ag[3];
    const float d4 = a1.x - (float)ag[4], d5 = a1.y - (float)ag[5];
    const float d6 = a1.z - (float)ag[6], d7 = a1.w - (float)ag[7];
    lsum += d0 * d0 + d1 * d1 + d2 * d2 + d3 * d3 + d4 * d4 + d5 * d5 +
            d6 * d6 + d7 * d7;
  }
#pragma unroll
  for (int m = 1; m < 64; m <<= 1) lsum += __shfl_xor(lsum, m, 64);
  if (lane == 0) sSum[wid] = lsum;
  __syncthreads();
  if (t == 0) {
    float s = 0.0f;
#pragma unroll
    for (int w = 0; w < 8; ++w) s += sSum[w];
    partials[bid] = s;
  }
}

__global__ __launch_bounds__(256) void final_reduce(
    const float* __restrict__ partials, float* __restrict__ out) {
  __shared__ float sS[4];
  const int t = threadIdx.x;
  float v = partials[t]; // exactly 256 partials
#pragma unroll
  for (int m = 1; m < 64; m <<= 1) v += __shfl_xor(v, m, 64);
  if ((t & 63) == 0) sS[t >> 6] = v;
  __syncthreads();
  if (t == 0)
    out[0] = (sS[0] + sS[1] + sS[2] + sS[3]) *
             (1.0f / ((float)N_ROWS * (float)D_DIM));
}

extern "C" void kernel_launch(void* const* d_in, const int* in_sizes, int n_in,
                              void* d_out, int out_size, void* d_ws,
                              size_t ws_size, hipStream_t stream) {
  const float* qf = (const float*)d_in[0];  // [32768][512]
  const float* itf = (const float*)d_in[1]; // [4096][512]
  char* ws = (char*)d_ws;
  unsigned char* pk2 = (unsigned char*)ws;                       // 2 MB fp8
  _Float16* ihl = (_Float16*)(ws + (size_t)M_ITEMS * D_DIM);     // 4 MB fp16
  float* partials =
      (float*)(ws + (size_t)M_ITEMS * D_DIM + (size_t)M_ITEMS * D_DIM * 2);
  float* out = (float*)d_out;

  cast_f32_f16<<<512, 256, 0, stream>>>(itf, ihl, M_ITEMS * D_DIM / 4);
  pack_items_fp8<<<512, 256, 0, stream>>>(itf, pk2);
  score_mse<<<N_ROWS / BM, 512, 0, stream>>>(qf, pk2, ihl, partials);
  final_reduce<<<1, 256, 0, stream>>>(partials, out);
}

// Round 21
// 117.666 us; speedup vs baseline: 4.8736x; 4.8736x over previous
//
#include <hip/hip_runtime.h>
#include <hip/hip_bf16.h>
#include <stdint.h>

// GatheringLoss: score = q[32768x512] @ items[4096x512]^T, idx = argmax_row,
// out = mean((q - items[idx])^2).
// R21: R20 spill repair. R20's full unroll of the kc64 loop hoisted all 8
// chunks' A/B loads into registers -> acc spilled to scratch (WRITE_SIZE
// 676MB, 573us). Fix: #pragma unroll 1 on kc64 (R19's proven granularity);
// fc inner loop stays unrolled (4 bv + 2 av + acc ~ 230 regs, fits).
// Keeps R20's validated (absmax 0.0) clean addressing: pk2[g][kc64][col][64B]
// contiguous i32x8 B loads, pitch-528 A LDS (no XOR), hoisted lane bases.
// Fold / butterfly / sV-sI merge / MSE epilogue = trusted lineage.
// ws: [0,2MB) pk2 fp8 packed items | [+4MB) ihl fp16 items | [+1KB) partials

#define D_DIM 512
#define M_ITEMS 4096
#define N_ROWS 32768
#define BM 128
#define GCOLS 512            // cols per group
#define NG (M_ITEMS / GCOLS) // 8 groups
#define APITCH 528           // A LDS row pitch (512 + 16B pad)

typedef _Float16 half8 __attribute__((ext_vector_type(8)));
typedef _Float16 half4h __attribute__((ext_vector_type(4)));
typedef float f32x16 __attribute__((ext_vector_type(16)));
typedef float f32x4v __attribute__((ext_vector_type(4)));
typedef int i32x8 __attribute__((ext_vector_type(8)));

__device__ inline unsigned pack4_fp8(float a, float b, float c, float d) {
  int v = 0;
  v = __builtin_amdgcn_cvt_pk_fp8_f32(a, b, v, false); // bytes 0,1
  v = __builtin_amdgcn_cvt_pk_fp8_f32(c, d, v, true);  // bytes 2,3
  return (unsigned)v;
}

__global__ __launch_bounds__(256) void cast_f32_f16(
    const float* __restrict__ in, _Float16* __restrict__ out, int n4) {
  const int stride = gridDim.x * blockDim.x;
  for (int i = blockIdx.x * blockDim.x + threadIdx.x; i < n4; i += stride) {
    const f32x4v v = reinterpret_cast<const f32x4v*>(in)[i];
    half4h h;
    h.x = (_Float16)v.x;
    h.y = (_Float16)v.y;
    h.z = (_Float16)v.z;
    h.w = (_Float16)v.w;
    reinterpret_cast<half4h*>(out)[i] = h;
  }
}

// pk2[g][kc64][c][64]: 16B unit u -> q=u&3, c=(u>>2)&511, kc64=(u>>11)&7,
// g=u>>14. Holds items[g*512+c][kc64*64 + q*16 .. +16) as fp8.
__global__ __launch_bounds__(256) void pack_items_fp8(
    const float* __restrict__ itf, unsigned char* __restrict__ pk2) {
  const int u = blockIdx.x * blockDim.x + threadIdx.x; // 0..131071
  const int q = u & 3;
  const int c = (u >> 2) & 511;
  const int kc64 = (u >> 11) & 7;
  const int g = u >> 14;
  const int m = g * 512 + c;
  const float* src = itf + (size_t)m * D_DIM + kc64 * 64 + q * 16;
  const f32x4v a = *reinterpret_cast<const f32x4v*>(src);
  const f32x4v b = *reinterpret_cast<const f32x4v*>(src + 4);
  const f32x4v cc = *reinterpret_cast<const f32x4v*>(src + 8);
  const f32x4v d = *reinterpret_cast<const f32x4v*>(src + 12);
  uint4 o;
  o.x = pack4_fp8(a.x, a.y, a.z, a.w);
  o.y = pack4_fp8(b.x, b.y, b.z, b.w);
  o.z = pack4_fp8(cc.x, cc.y, cc.z, cc.w);
  o.w = pack4_fp8(d.x, d.y, d.z, d.w);
  *reinterpret_cast<uint4*>(pk2 + (size_t)u * 16) = o;
}

__global__ __launch_bounds__(512, 2) void score_mse(
    const float* __restrict__ qf, const unsigned char* __restrict__ pk2,
    const _Float16* __restrict__ ihl, float* __restrict__ partials) {
  __shared__ __align__(16) unsigned char Alds8[BM * APITCH]; // 67.5 KiB
  __shared__ float sV[4][BM];
  __shared__ int sI[4][BM];
  __shared__ float sSum[8];

  const int t = threadIdx.x; // 0..511
  const int lane = t & 63;
  const int wid = t >> 6;  // 0..7
  const int wm = wid >> 2; // 0..1 (row half: 64 rows)
  const int wn = wid & 3;  // 0..3 (col quarter of 512: 128 cols)
  const int l31 = lane & 31;
  const int hsel = lane >> 5; // 0..1

  // T1: XCD chunking (grid 256 = 8 XCD x 32)
  const int bid = blockIdx.x;
  const int rb = (bid & 7) * 32 + (bid >> 3);
  const int row0 = rb * BM;

  // --- prologue: cast this block's 128 q rows f32->fp8 into Alds8 (linear
  // within row, pitch 528). 4096 16B-units, 8 per thread.
#pragma unroll
  for (int i = 0; i < 8; ++i) {
    const int f = i * 512 + t; // 0..4095
    const int r = f >> 5;
    const int u = f & 31;
    const float* src = qf + (size_t)(row0 + r) * D_DIM + u * 16;
    const f32x4v a = *(const f32x4v*)(src);
    const f32x4v b = *(const f32x4v*)(src + 4);
    const f32x4v c = *(const f32x4v*)(src + 8);
    const f32x4v d = *(const f32x4v*)(src + 12);
    uint4 o;
    o.x = pack4_fp8(a.x, a.y, a.z, a.w);
    o.y = pack4_fp8(b.x, b.y, b.z, b.w);
    o.z = pack4_fp8(c.x, c.y, c.z, c.w);
    o.w = pack4_fp8(d.x, d.y, d.z, d.w);
    *reinterpret_cast<uint4*>(Alds8 + (size_t)r * APITCH + u * 16) = o;
  }
  __syncthreads();

  f32x16 acc[2][4];
#pragma unroll
  for (int fr = 0; fr < 2; ++fr)
#pragma unroll
    for (int fc = 0; fc < 4; ++fc) acc[fr][fc] = (f32x16)(0.0f);
  float rmax[2][16];
  unsigned rid16[16]; // packed idx: bits [15:0]=fr0, [31:16]=fr1
#pragma unroll
  for (int rg = 0; rg < 16; ++rg) {
    rmax[0][rg] = -3.0e38f;
    rmax[1][rg] = -3.0e38f;
    rid16[rg] = 0u;
  }

  // Hoisted lane bases. A: row = wm*64 + {l31, 32+l31}, k-half by hsel.
  const unsigned char* Aptr0 =
      Alds8 + (size_t)(wm * 64 + l31) * APITCH + hsel * 32;
  const unsigned char* Aptr1 = Aptr0 + (size_t)32 * APITCH;
  // B: lane offset within a (g,kc64) 32KB panel: col*64 + hsel*32.
  const size_t bo0 = ((size_t)(wn * 128 + l31) << 6) + hsel * 32;

#pragma unroll 1
  for (int g = 0; g < NG; ++g) {
    const unsigned char* pgrp = pk2 + ((size_t)g << 18); // g * 256KB
#pragma unroll 1
    for (int kc64 = 0; kc64 < 8; ++kc64) { // unroll 1: no load hoist/spill
      const unsigned char* pchunk = pgrp + (kc64 << 15); // + kc64 * 32KB
      const i32x8 av0 = *(const i32x8*)(Aptr0 + kc64 * 64);
      const i32x8 av1 = *(const i32x8*)(Aptr1 + kc64 * 64);
#pragma unroll
      for (int fc = 0; fc < 4; ++fc) {
        const i32x8 bv = *(const i32x8*)(pchunk + bo0 + fc * 2048);
        // cbsz=0 (fp8 e4m3), blgp=0, scale 127 = x1.0 (exact)
        acc[0][fc] = __builtin_amdgcn_mfma_scale_f32_32x32x64_f8f6f4(
            av0, bv, acc[0][fc], 0, 0, 0, 127, 0, 127);
        acc[1][fc] = __builtin_amdgcn_mfma_scale_f32_32x32x64_f8f6f4(
            av1, bv, acc[1][fc], 0, 0, 0, 127, 0, 127);
      }
    }
    // --- group fold (trusted lineage): cols ascend with fc and g ->
    // strict > keeps lowest index.
    {
      const int colbase_ = g * GCOLS + wn * 128 + l31;
#pragma unroll
      for (int fr = 0; fr < 2; ++fr)
#pragma unroll
        for (int rg = 0; rg < 16; ++rg) {
          float v_ = acc[fr][0][rg];
          int c_ = colbase_;
#pragma unroll
          for (int fc = 1; fc < 4; ++fc) {
            const float vv_ = acc[fr][fc][rg];
            if (vv_ > v_) {
              v_ = vv_;
              c_ = colbase_ + fc * 32;
            }
          }
          if (v_ > rmax[fr][rg]) {
            rmax[fr][rg] = v_;
            rid16[rg] = (rid16[rg] & (fr ? 0x0000FFFFu : 0xFFFF0000u)) |
                        ((unsigned)c_ << (fr * 16));
          }
        }
#pragma unroll
      for (int fr = 0; fr < 2; ++fr)
#pragma unroll
        for (int fc = 0; fc < 4; ++fc) acc[fr][fc] = (f32x16)(0.0f);
    }
  }

  // --- argmax block reduce. C/D layout (m74/m101): col = lane&31,
  // row = (rg&3) + 8*(rg>>2) + 4*(lane>>5).
  float bv = -3.0e38f;
  int bi = 0;
#pragma unroll
  for (int fr = 0; fr < 2; ++fr)
#pragma unroll
    for (int rg = 0; rg < 16; ++rg) {
      float v = rmax[fr][rg];
      int c = (int)((rid16[rg] >> (fr * 16)) & 0xFFFFu);
#pragma unroll
      for (int m = 1; m < 32; m <<= 1) {
        const float ov = __shfl_xor(v, m, 64);
        const int oc = __shfl_xor(c, m, 64);
        if (ov > v || (ov == v && oc < c)) {
          v = ov;
          c = oc;
        }
      }
      if (l31 == fr * 16 + rg) {
        bv = v;
        bi = c;
      }
    }
  const int e = l31;
  const int row_local =
      wm * 64 + (e >> 4) * 32 + ((e & 3) + 8 * ((e >> 2) & 3)) + 4 * hsel;

  sV[wn][row_local] = bv;
  sI[wn][row_local] = bi;
  __syncthreads();
  if (t < BM) {
    float fv = sV[0][t];
    int fi = sI[0][t];
#pragma unroll
    for (int w = 1; w < 4; ++w) {
      const float v = sV[w][t];
      const int ii = sI[w][t];
      if (v > fv || (v == fv && ii < fi)) {
        fv = v;
        fi = ii;
      }
    }
    sI[0][t] = fi; // merged winner per row
  }
  __syncthreads();

  // --- fused MSE epilogue: wave wid handles rows wid*16..+15.
  // q EXACT from global f32; gathered item from fp16 ihl.
  float lsum = 0.0f;
#pragma unroll 1
  for (int rr = 0; rr < 16; ++rr) {
    const int r = wid * 16 + rr;
    const int fi = sI[0][r];
    const float* qr = qf + (size_t)(row0 + r) * D_DIM + lane * 8;
    const f32x4v a0 = *(const f32x4v*)(qr);
    const f32x4v a1 = *(const f32x4v*)(qr + 4);
    const half8 ag = *(const half8*)(ihl + (size_t)fi * D_DIM + lane * 8);
    const float d0 = a0.x - (float)ag[0], d1 = a0.y - (float)ag[1];
    const float d2 = a0.z - (float)ag[2], d3 = a0.w - (float)ag[3];
    const float d4 = a1.x - (float)ag[4], d5 = a1.y - (float)ag[5];
    const float d6 = a1.z - (float)ag[6], d7 = a1.w - (float)ag[7];
    lsum += d0 * d0 + d1 * d1 + d2 * d2 + d3 * d3 + d4 * d4 + d5 * d5 +
            d6 * d6 + d7 * d7;
  }
#pragma unroll
  for (int m = 1; m < 64; m <<= 1) lsum += __shfl_xor(lsum, m, 64);
  if (lane == 0) sSum[wid] = lsum;
  __syncthreads();
  if (t == 0) {
    float s = 0.0f;
#pragma unroll
    for (int w = 0; w < 8; ++w) s += sSum[w];
    partials[bid] = s;
  }
}

__global__ __launch_bounds__(256) void final_reduce(
    const float* __restrict__ partials, float* __restrict__ out) {
  __shared__ float sS[4];
  const int t = threadIdx.x;
  float v = partials[t]; // exactly 256 partials
#pragma unroll
  for (int m = 1; m < 64; m <<= 1) v += __shfl_xor(v, m, 64);
  if ((t & 63) == 0) sS[t >> 6] = v;
  __syncthreads();
  if (t == 0)
    out[0] = (sS[0] + sS[1] + sS[2] + sS[3]) *
             (1.0f / ((float)N_ROWS * (float)D_DIM));
}

extern "C" void kernel_launch(void* const* d_in, const int* in_sizes, int n_in,
                              void* d_out, int out_size, void* d_ws,
                              size_t ws_size, hipStream_t stream) {
  const float* qf = (const float*)d_in[0];  // [32768][512]
  const float* itf = (const float*)d_in[1]; // [4096][512]
  char* ws = (char*)d_ws;
  unsigned char* pk2 = (unsigned char*)ws;                       // 2 MB fp8
  _Float16* ihl = (_Float16*)(ws + (size_t)M_ITEMS * D_DIM);     // 4 MB fp16
  float* partials =
      (float*)(ws + (size_t)M_ITEMS * D_DIM + (size_t)M_ITEMS * D_DIM * 2);
  float* out = (float*)d_out;

  cast_f32_f16<<<512, 256, 0, stream>>>(itf, ihl, M_ITEMS * D_DIM / 4);
  pack_items_fp8<<<512, 256, 0, stream>>>(itf, pk2);
  score_mse<<<N_ROWS / BM, 512, 0, stream>>>(qf, pk2, ihl, partials);
  final_reduce<<<1, 256, 0, stream>>>(partials, out);
}

// Round 22
// 114.215 us; speedup vs baseline: 5.0209x; 1.0302x over previous
//
#include <hip/hip_runtime.h>
#include <hip/hip_bf16.h>
#include <stdint.h>

// GatheringLoss: score = q[32768x512] @ items[4096x512]^T, idx = argmax_row,
// out = mean((q - items[idx])^2).
// R22: true depth-1 software pipeline, funded by halving acc. Col work per
// group split into 2 halves of 2 fc -> acc[2][2]=64 VGPR (-64); freed regs
// buy double-buffered av+bv (statically named sets A/B): iter n+1's loads
// issue BEFORE iter n's MFMAs. 128 iters x 4 MFMA (same pipe work). Col
// order g->half->fc still ascending (tie rule exact). pk2 layout, pitch-528
// A LDS, fold/butterfly/merge/MSE = R21 lineage (absmax 0.0).
// ws: [0,2MB) pk2 fp8 packed items | [+4MB) ihl fp16 items | [+1KB) partials

#define D_DIM 512
#define M_ITEMS 4096
#define N_ROWS 32768
#define BM 128
#define GCOLS 512            // cols per group
#define NG (M_ITEMS / GCOLS) // 8 groups
#define APITCH 528           // A LDS row pitch (512 + 16B pad)
#define NIT 128              // 8 g x 2 half x 8 kc64

typedef _Float16 half8 __attribute__((ext_vector_type(8)));
typedef _Float16 half4h __attribute__((ext_vector_type(4)));
typedef float f32x16 __attribute__((ext_vector_type(16)));
typedef float f32x4v __attribute__((ext_vector_type(4)));
typedef int i32x8 __attribute__((ext_vector_type(8)));

__device__ inline unsigned pack4_fp8(float a, float b, float c, float d) {
  int v = 0;
  v = __builtin_amdgcn_cvt_pk_fp8_f32(a, b, v, false); // bytes 0,1
  v = __builtin_amdgcn_cvt_pk_fp8_f32(c, d, v, true);  // bytes 2,3
  return (unsigned)v;
}

__global__ __launch_bounds__(256) void cast_f32_f16(
    const float* __restrict__ in, _Float16* __restrict__ out, int n4) {
  const int stride = gridDim.x * blockDim.x;
  for (int i = blockIdx.x * blockDim.x + threadIdx.x; i < n4; i += stride) {
    const f32x4v v = reinterpret_cast<const f32x4v*>(in)[i];
    half4h h;
    h.x = (_Float16)v.x;
    h.y = (_Float16)v.y;
    h.z = (_Float16)v.z;
    h.w = (_Float16)v.w;
    reinterpret_cast<half4h*>(out)[i] = h;
  }
}

// pk2[g][kc64][c][64]: 16B unit u -> q=u&3, c=(u>>2)&511, kc64=(u>>11)&7,
// g=u>>14. Holds items[g*512+c][kc64*64 + q*16 .. +16) as fp8.
__global__ __launch_bounds__(256) void pack_items_fp8(
    const float* __restrict__ itf, unsigned char* __restrict__ pk2) {
  const int u = blockIdx.x * blockDim.x + threadIdx.x; // 0..131071
  const int q = u & 3;
  const int c = (u >> 2) & 511;
  const int kc64 = (u >> 11) & 7;
  const int g = u >> 14;
  const int m = g * 512 + c;
  const float* src = itf + (size_t)m * D_DIM + kc64 * 64 + q * 16;
  const f32x4v a = *reinterpret_cast<const f32x4v*>(src);
  const f32x4v b = *reinterpret_cast<const f32x4v*>(src + 4);
  const f32x4v cc = *reinterpret_cast<const f32x4v*>(src + 8);
  const f32x4v d = *reinterpret_cast<const f32x4v*>(src + 12);
  uint4 o;
  o.x = pack4_fp8(a.x, a.y, a.z, a.w);
  o.y = pack4_fp8(b.x, b.y, b.z, b.w);
  o.z = pack4_fp8(cc.x, cc.y, cc.z, cc.w);
  o.w = pack4_fp8(d.x, d.y, d.z, d.w);
  *reinterpret_cast<uint4*>(pk2 + (size_t)u * 16) = o;
}

__global__ __launch_bounds__(512, 2) void score_mse(
    const float* __restrict__ qf, const unsigned char* __restrict__ pk2,
    const _Float16* __restrict__ ihl, float* __restrict__ partials) {
  __shared__ __align__(16) unsigned char Alds8[BM * APITCH]; // 67.5 KiB
  __shared__ float sV[4][BM];
  __shared__ int sI[4][BM];
  __shared__ float sSum[8];

  const int t = threadIdx.x; // 0..511
  const int lane = t & 63;
  const int wid = t >> 6;  // 0..7
  const int wm = wid >> 2; // 0..1 (row half: 64 rows)
  const int wn = wid & 3;  // 0..3 (col quarter of 512: 128 cols)
  const int l31 = lane & 31;
  const int hsel = lane >> 5; // 0..1

  // T1: XCD chunking (grid 256 = 8 XCD x 32)
  const int bid = blockIdx.x;
  const int rb = (bid & 7) * 32 + (bid >> 3);
  const int row0 = rb * BM;

  // --- prologue: cast this block's 128 q rows f32->fp8 into Alds8 (linear
  // within row, pitch 528). 4096 16B-units, 8 per thread.
#pragma unroll
  for (int i = 0; i < 8; ++i) {
    const int f = i * 512 + t; // 0..4095
    const int r = f >> 5;
    const int u = f & 31;
    const float* src = qf + (size_t)(row0 + r) * D_DIM + u * 16;
    const f32x4v a = *(const f32x4v*)(src);
    const f32x4v b = *(const f32x4v*)(src + 4);
    const f32x4v c = *(const f32x4v*)(src + 8);
    const f32x4v d = *(const f32x4v*)(src + 12);
    uint4 o;
    o.x = pack4_fp8(a.x, a.y, a.z, a.w);
    o.y = pack4_fp8(b.x, b.y, b.z, b.w);
    o.z = pack4_fp8(c.x, c.y, c.z, c.w);
    o.w = pack4_fp8(d.x, d.y, d.z, d.w);
    *reinterpret_cast<uint4*>(Alds8 + (size_t)r * APITCH + u * 16) = o;
  }
  __syncthreads();

  f32x16 acc[2][2];
#pragma unroll
  for (int fr = 0; fr < 2; ++fr)
#pragma unroll
    for (int fc = 0; fc < 2; ++fc) acc[fr][fc] = (f32x16)(0.0f);
  float rmax[2][16];
  unsigned rid16[16]; // packed idx: bits [15:0]=fr0, [31:16]=fr1
#pragma unroll
  for (int rg = 0; rg < 16; ++rg) {
    rmax[0][rg] = -3.0e38f;
    rmax[1][rg] = -3.0e38f;
    rid16[rg] = 0u;
  }

  // Hoisted lane bases. A: row = wm*64 + {l31, 32+l31}, k-half by hsel.
  const unsigned char* Aptr0 =
      Alds8 + (size_t)(wm * 64 + l31) * APITCH + hsel * 32;
  const unsigned char* Aptr1 = Aptr0 + (size_t)32 * APITCH;
  // B lane base: (wn*128 + l31)*64 + hsel*32; iter offset is uniform.
  const unsigned char* pB = pk2 + ((size_t)(wn * 128 + l31) << 6) + hsel * 32;

// iter n: g = n>>4, half = (n>>3)&1, kc64 = n&7.
#define BOFF(n)                                                                \
  ((((size_t)((n) >> 4)) << 18) + (((size_t)((n) & 7)) << 15) +                \
   (((size_t)(((n) >> 3) & 1)) << 12))

#define LOADBV(n, B0, B1)                                                      \
  do {                                                                         \
    const unsigned char* p_ = pB + BOFF(n);                                    \
    B0 = *(const i32x8*)(p_);                                                  \
    B1 = *(const i32x8*)(p_ + 2048);                                           \
  } while (0)

#define LOADAV(n, A0, A1)                                                      \
  do {                                                                         \
    const int ko_ = ((n) & 7) * 64;                                            \
    A0 = *(const i32x8*)(Aptr0 + ko_);                                         \
    A1 = *(const i32x8*)(Aptr1 + ko_);                                         \
  } while (0)

// body: prefetch iter n+1 into the alternate set, then 4 MFMAs, then
// (runtime) per-(g,half) fold — R16-proven in-loop form.
#define PBODY(n, A0c, A1c, B0c, B1c, A0n, A1n, B0n, B1n)                       \
  do {                                                                         \
    if ((n) + 1 < NIT) {                                                       \
      LOADBV((n) + 1, B0n, B1n);                                               \
      LOADAV((n) + 1, A0n, A1n);                                               \
    }                                                                          \
    acc[0][0] = __builtin_amdgcn_mfma_scale_f32_32x32x64_f8f6f4(               \
        A0c, B0c, acc[0][0], 0, 0, 0, 127, 0, 127);                            \
    acc[0][1] = __builtin_amdgcn_mfma_scale_f32_32x32x64_f8f6f4(               \
        A0c, B1c, acc[0][1], 0, 0, 0, 127, 0, 127);                            \
    acc[1][0] = __builtin_amdgcn_mfma_scale_f32_32x32x64_f8f6f4(               \
        A1c, B0c, acc[1][0], 0, 0, 0, 127, 0, 127);                            \
    acc[1][1] = __builtin_amdgcn_mfma_scale_f32_32x32x64_f8f6f4(               \
        A1c, B1c, acc[1][1], 0, 0, 0, 127, 0, 127);                            \
    if (((n) & 7) == 7) {                                                      \
      const int colbase_ =                                                     \
          ((n) >> 4) * GCOLS + (((n) >> 3) & 1) * 64 + wn * 128 + l31;         \
      _Pragma("unroll") for (int fr = 0; fr < 2; ++fr)                         \
          _Pragma("unroll") for (int rg = 0; rg < 16; ++rg) {                  \
        float v_ = acc[fr][0][rg];                                             \
        int c_ = colbase_;                                                     \
        const float vv_ = acc[fr][1][rg];                                      \
        if (vv_ > v_) {                                                        \
          v_ = vv_;                                                            \
          c_ = colbase_ + 32;                                                  \
        }                                                                      \
        if (v_ > rmax[fr][rg]) {                                               \
          rmax[fr][rg] = v_;                                                   \
          rid16[rg] = (rid16[rg] & (fr ? 0x0000FFFFu : 0xFFFF0000u)) |         \
                      ((unsigned)c_ << (fr * 16));                             \
        }                                                                      \
      }                                                                        \
      _Pragma("unroll") for (int fr = 0; fr < 2; ++fr)                         \
          _Pragma("unroll") for (int fc = 0; fc < 2; ++fc) acc[fr][fc] =       \
              (f32x16)(0.0f);                                                  \
    }                                                                          \
  } while (0)

  i32x8 avA0, avA1, avB0, avB1, bvA0, bvA1, bvB0, bvB1;
  LOADBV(0, bvA0, bvA1);
  LOADAV(0, avA0, avA1);
#pragma unroll 1
  for (int n = 0; n < NIT; n += 2) {
    PBODY(n, avA0, avA1, bvA0, bvA1, avB0, avB1, bvB0, bvB1);
    PBODY(n + 1, avB0, avB1, bvB0, bvB1, avA0, avA1, bvA0, bvA1);
  }

  // --- argmax block reduce. C/D layout (m74/m101): col = lane&31,
  // row = (rg&3) + 8*(rg>>2) + 4*(lane>>5).
  float bv = -3.0e38f;
  int bi = 0;
#pragma unroll
  for (int fr = 0; fr < 2; ++fr)
#pragma unroll
    for (int rg = 0; rg < 16; ++rg) {
      float v = rmax[fr][rg];
      int c = (int)((rid16[rg] >> (fr * 16)) & 0xFFFFu);
#pragma unroll
      for (int m = 1; m < 32; m <<= 1) {
        const float ov = __shfl_xor(v, m, 64);
        const int oc = __shfl_xor(c, m, 64);
        if (ov > v || (ov == v && oc < c)) {
          v = ov;
          c = oc;
        }
      }
      if (l31 == fr * 16 + rg) {
        bv = v;
        bi = c;
      }
    }
  const int e = l31;
  const int row_local =
      wm * 64 + (e >> 4) * 32 + ((e & 3) + 8 * ((e >> 2) & 3)) + 4 * hsel;

  sV[wn][row_local] = bv;
  sI[wn][row_local] = bi;
  __syncthreads();
  if (t < BM) {
    float fv = sV[0][t];
    int fi = sI[0][t];
#pragma unroll
    for (int w = 1; w < 4; ++w) {
      const float v = sV[w][t];
      const int ii = sI[w][t];
      if (v > fv || (v == fv && ii < fi)) {
        fv = v;
        fi = ii;
      }
    }
    sI[0][t] = fi; // merged winner per row
  }
  __syncthreads();

  // --- fused MSE epilogue: wave wid handles rows wid*16..+15.
  // q EXACT from global f32; gathered item from fp16 ihl.
  float lsum = 0.0f;
#pragma unroll 1
  for (int rr = 0; rr < 16; ++rr) {
    const int r = wid * 16 + rr;
    const int fi = sI[0][r];
    const float* qr = qf + (size_t)(row0 + r) * D_DIM + lane * 8;
    const f32x4v a0 = *(const f32x4v*)(qr);
    const f32x4v a1 = *(const f32x4v*)(qr + 4);
    const half8 ag = *(const half8*)(ihl + (size_t)fi * D_DIM + lane * 8);
    const float d0 = a0.x - (float)ag[0], d1 = a0.y - (float)ag[1];
    const float d2 = a0.z - (float)ag[2], d3 = a0.w - (float)ag[3];
    const float d4 = a1.x - (float)ag[4], d5 = a1.y - (float)ag[5];
    const float d6 = a1.z - (float)ag[6], d7 = a1.w - (float)ag[7];
    lsum += d0 * d0 + d1 * d1 + d2 * d2 + d3 * d3 + d4 * d4 + d5 * d5 +
            d6 * d6 + d7 * d7;
  }
#pragma unroll
  for (int m = 1; m < 64; m <<= 1) lsum += __shfl_xor(lsum, m, 64);
  if (lane == 0) sSum[wid] = lsum;
  __syncthreads();
  if (t == 0) {
    float s = 0.0f;
#pragma unroll
    for (int w = 0; w < 8; ++w) s += sSum[w];
    partials[bid] = s;
  }
}

__global__ __launch_bounds__(256) void final_reduce(
    const float* __restrict__ partials, float* __restrict__ out) {
  __shared__ float sS[4];
  const int t = threadIdx.x;
  float v = partials[t]; // exactly 256 partials
#pragma unroll
  for (int m = 1; m < 64; m <<= 1) v += __shfl_xor(v, m, 64);
  if ((t & 63) == 0) sS[t >> 6] = v;
  __syncthreads();
  if (t == 0)
    out[0] = (sS[0] + sS[1] + sS[2] + sS[3]) *
             (1.0f / ((float)N_ROWS * (float)D_DIM));
}

extern "C" void kernel_launch(void* const* d_in, const int* in_sizes, int n_in,
                              void* d_out, int out_size, void* d_ws,
                              size_t ws_size, hipStream_t stream) {
  const float* qf = (const float*)d_in[0];  // [32768][512]
  const float* itf = (const float*)d_in[1]; // [4096][512]
  char* ws = (char*)d_ws;
  unsigned char* pk2 = (unsigned char*)ws;                       // 2 MB fp8
  _Float16* ihl = (_Float16*)(ws + (size_t)M_ITEMS * D_DIM);     // 4 MB fp16
  float* partials =
      (float*)(ws + (size_t)M_ITEMS * D_DIM + (size_t)M_ITEMS * D_DIM * 2);
  float* out = (float*)d_out;

  cast_f32_f16<<<512, 256, 0, stream>>>(itf, ihl, M_ITEMS * D_DIM / 4);
  pack_items_fp8<<<512, 256, 0, stream>>>(itf, pk2);
  score_mse<<<N_ROWS / BM, 512, 0, stream>>>(qf, pk2, ihl, partials);
  final_reduce<<<1, 256, 0, stream>>>(partials, out);
}